// Round 14
// baseline (144.347 us; speedup 1.0000x reference)
//
#include <hip/hip_runtime.h>
#include <hip/hip_bf16.h>

typedef __bf16 bf16;
typedef __bf16 bf16x8 __attribute__((ext_vector_type(8)));
typedef __bf16 bf16x4 __attribute__((ext_vector_type(4)));
typedef float  f32x4  __attribute__((ext_vector_type(4)));
typedef float  f32x16 __attribute__((ext_vector_type(16)));
typedef unsigned int u32;
typedef u32 u32x4 __attribute__((ext_vector_type(4)));

constexpr int BB = 2, C = 512, NN = 8192, CK = 128;

__device__ __forceinline__ u32 cvt_pk_bf16(float lo, float hi) {
    u32 r;
    asm("v_cvt_pk_bf16_f32 %0, %1, %2" : "=v"(r) : "v"(lo), "v"(hi));
    return r;
}
__device__ __forceinline__ void pl32_swap(u32& a, u32& b) {
    asm("v_permlane32_swap_b32 %0, %1" : "+v"(a), "+v"(b));
}

// ---------------- Kernel 1: QKV projection, XCD-swizzled (x re-reads hit L2) ----------------
__global__ __launch_bounds__(256) void k_qkv(
    const float* __restrict__ x,
    const float* __restrict__ Wq, const float* __restrict__ bq,
    const float* __restrict__ Wk, const float* __restrict__ bk,
    const float* __restrict__ Wv, const float* __restrict__ bv,
    bf16* __restrict__ qkv_ws)
{
    const int t = threadIdx.x;
    const int lane = t & 63, w = t >> 6;
    const int lr = lane & 15, lg = lane >> 4;

    const int lin = blockIdx.x;
    const int rid = (lin & 7) * 48 + (lin >> 3);   // bijective over 384
    const int n0 = (rid / 6) * 128;
    const int sub = rid % 6;
    const int which = sub >> 1;
    const int b = sub & 1;

    const float* W    = which == 0 ? Wq : (which == 1 ? Wk : Wv);
    const float* bias = which == 0 ? bq : (which == 1 ? bk : bv);
    bf16* out = qkv_ws + (size_t)which * BB * NN * CK;

    __shared__ __align__(16) char s_xT[128 * 144];
    __shared__ __align__(16) char s_w [128 * 144];

    f32x4 acc[2][8];
#pragma unroll
    for (int m = 0; m < 2; m++)
#pragma unroll
        for (int j = 0; j < 8; j++) acc[m][j] = (f32x4){0.f, 0.f, 0.f, 0.f};

    const float* xb = x + (size_t)b * C * NN;

    const int tok4 = (t & 31) * 4;
    const int c8   = (t >> 5) * 8;
    const int ob   = t >> 2;
    const int c16  = (t & 3) * 16;

    for (int kt = 0; kt < C; kt += 64) {
        __syncthreads();
        {
            float4 v[8];
#pragma unroll
            for (int i = 0; i < 8; i++)
                v[i] = *(const float4*)(xb + (size_t)(kt + c8 + i) * NN + n0 + tok4);
#pragma unroll
            for (int j = 0; j < 4; j++) {
                int tok = tok4 + j;
                bf16x8 pk = { (bf16)v[0].x, (bf16)v[1].x, (bf16)v[2].x, (bf16)v[3].x,
                              (bf16)v[4].x, (bf16)v[5].x, (bf16)v[6].x, (bf16)v[7].x };
                if (j == 1) pk = (bf16x8){ (bf16)v[0].y, (bf16)v[1].y, (bf16)v[2].y, (bf16)v[3].y,
                                           (bf16)v[4].y, (bf16)v[5].y, (bf16)v[6].y, (bf16)v[7].y };
                if (j == 2) pk = (bf16x8){ (bf16)v[0].z, (bf16)v[1].z, (bf16)v[2].z, (bf16)v[3].z,
                                           (bf16)v[4].z, (bf16)v[5].z, (bf16)v[6].z, (bf16)v[7].z };
                if (j == 3) pk = (bf16x8){ (bf16)v[0].w, (bf16)v[1].w, (bf16)v[2].w, (bf16)v[3].w,
                                           (bf16)v[4].w, (bf16)v[5].w, (bf16)v[6].w, (bf16)v[7].w };
                int off = tok * 144 + ((c8 * 2) ^ ((((tok >> 2) & 7)) << 4));
                *(bf16x8*)(s_xT + off) = pk;
            }
        }
#pragma unroll
        for (int p = 0; p < 2; p++) {
            int o = ob + p * 64;
            const float* wp = W + (size_t)o * C + kt + c16;
            float4 a0 = *(const float4*)(wp);
            float4 a1 = *(const float4*)(wp + 4);
            float4 a2 = *(const float4*)(wp + 8);
            float4 a3 = *(const float4*)(wp + 12);
            bf16x8 p0 = { (bf16)a0.x, (bf16)a0.y, (bf16)a0.z, (bf16)a0.w,
                          (bf16)a1.x, (bf16)a1.y, (bf16)a1.z, (bf16)a1.w };
            bf16x8 p1 = { (bf16)a2.x, (bf16)a2.y, (bf16)a2.z, (bf16)a2.w,
                          (bf16)a3.x, (bf16)a3.y, (bf16)a3.z, (bf16)a3.w };
            int perm = ((o >> 2) & 7) << 4;
            *(bf16x8*)(s_w + o * 144 + ((c16 * 2) ^ perm)) = p0;
            *(bf16x8*)(s_w + o * 144 + ((c16 * 2 + 16) ^ perm)) = p1;
        }
        __syncthreads();
#pragma unroll
        for (int ks = 0; ks < 2; ks++) {
            bf16x8 af[2];
#pragma unroll
            for (int m = 0; m < 2; m++) {
                int row = w * 32 + m * 16 + lr;
                af[m] = *(const bf16x8*)(s_xT + row * 144 + ((ks * 64 + lg * 16) ^ ((((row >> 2) & 7)) << 4)));
            }
#pragma unroll
            for (int j = 0; j < 8; j++) {
                int row = j * 16 + lr;
                bf16x8 bfr = *(const bf16x8*)(s_w + row * 144 + ((ks * 64 + lg * 16) ^ ((((row >> 2) & 7)) << 4)));
                acc[0][j] = __builtin_amdgcn_mfma_f32_16x16x32_bf16(af[0], bfr, acc[0][j], 0, 0, 0);
                acc[1][j] = __builtin_amdgcn_mfma_f32_16x16x32_bf16(af[1], bfr, acc[1][j], 0, 0, 0);
            }
        }
    }
#pragma unroll
    for (int m = 0; m < 2; m++)
#pragma unroll
        for (int j = 0; j < 8; j++) {
            int o = j * 16 + lr;
            float bia = bias[o];
#pragma unroll
            for (int r = 0; r < 4; r++) {
                int tok = n0 + w * 32 + m * 16 + lg * 4 + r;
                out[((size_t)b * NN + tok) * CK + o] = (bf16)(acc[m][j][r] + bia);
            }
        }
}

// ---------------- Kernel 2: flash attention, m==0, pipelined PV, anti-phase skew,
// split QK^T accumulator chains, bf16 Opart ----------------
__global__ __launch_bounds__(512, 2) void k_attn(
    const bf16* __restrict__ qkv_ws,
    bf16* __restrict__ Opart, float* __restrict__ Lw,
    int nsplit)
{
    const int t = threadIdx.x;
    const int lane = t & 63, w = t >> 6;      // 8 waves
    const int lq = lane & 31, hi = lane >> 5;
    const int phase = (w >> 2) & 1;           // one of each phase per SIMD

    const int total = 32 * BB * nsplit;
    const int chunkv = total >> 3;
    const int lin = blockIdx.x;
    const int rid = (lin & 7) * chunkv + (lin >> 3);
    const int qt = rid & 31;                  // 32 q-tiles of 256
    const int bs = rid >> 5;
    const int b = bs & 1, split = bs >> 1;

    const int q0 = qt * 256;
    const int kbeg = split * (NN / nsplit);
    const int nt = (NN / nsplit) / 64;

    const bf16* kg = qkv_ws + (size_t)BB * NN * CK;
    const bf16* vg = qkv_ws + (size_t)2 * BB * NN * CK;

    __shared__ __align__(16) char s_k[2][64 * 256];    // [key][dim], swz ((key&7)<<4)
    __shared__ __align__(16) char s_vt[3][128 * 128];  // [dim][key], swz (((d^(d>>3))&7)<<4)

    // per-lane LDS read bases (hi folded in)
    const int kb0 = lq * 256 + ((((lq & 7) ^ hi)) << 4);
    int vbs[4];
#pragma unroll
    for (int db = 0; db < 4; db++) {
        int d = db * 32 + lq;
        vbs[db] = d * 128 + (((((d ^ (d >> 3)) & 7) ^ hi)) << 4);
    }
    // staging (role-split: waves 0-3 K, 4-7 V^T)
    const int t2 = t & 255;
    const int sc = t2 & 15, sr = t2 >> 4;
    const int kw_base = (sr * 256 + sc * 16) ^ ((sr & 7) << 4);
    const int vw_base = (sc * 1024 + sr * 8) ^ ((sc & 7) << 4);

    // Q fragments pre-scaled by scale*log2e
    bf16x8 qf[8];
    {
        const float qs = 0.08838834764831845f * 1.4426950408889634f;
        const bf16* qp = qkv_ws + ((size_t)b * NN + q0 + w * 32 + lq) * CK + hi * 8;
#pragma unroll
        for (int ks = 0; ks < 8; ks++) {
            bf16x8 v = *(const bf16x8*)(qp + ks * 16);
#pragma unroll
            for (int i = 0; i < 8; i++) qf[ks][i] = (bf16)((float)v[i] * qs);
        }
    }

    f32x16 oacc[4];
#pragma unroll
    for (int db = 0; db < 4; db++)
#pragma unroll
        for (int i = 0; i < 16; i++) oacc[db][i] = 0.f;
    float lrun = 0.f;

    const bf16* kp = kg + ((size_t)b * NN + kbeg + sr) * CK + sc * 8;
    const bf16* vp = vg + ((size_t)b * NN + kbeg + sr * 4) * CK + sc * 8;
    bf16x8 stg[4];

    auto issue_loads = [&]() {
        if (w < 4) {
#pragma unroll
            for (int p = 0; p < 4; p++) stg[p] = *(const bf16x8*)(kp + (size_t)(16 * p) * CK);
        } else {
#pragma unroll
            for (int p = 0; p < 4; p++) stg[p] = *(const bf16x8*)(vp + (size_t)p * CK);
        }
        kp += (size_t)64 * CK;
        vp += (size_t)64 * CK;
    };

    auto write_lds = [&](int kbuf, int vbuf) {
        if (w < 4) {
            char* skw = s_k[kbuf] + kw_base;
#pragma unroll
            for (int p = 0; p < 4; p++)
                *(bf16x8*)(skw + p * 4096) = stg[p];
        } else {
            char* svw = s_vt[vbuf];
#pragma unroll
            for (int i = 0; i < 8; i++) {
                bf16x4 pk = { stg[0][i], stg[1][i], stg[2][i], stg[3][i] };
                *(bf16x4*)(svw + (vw_base ^ (i * 144))) = pk;   // i*128 | i*16
            }
        }
    };

    f32x16 sa0, sa1;
    auto do_qkt = [&](const char* sk) {
        // 4 independent accumulation chains (even/odd ks) to hide MFMA latency
        f32x16 a0e, a0o, a1e, a1o;
#pragma unroll
        for (int i = 0; i < 16; i++) { a0e[i] = 0.f; a0o[i] = 0.f; a1e[i] = 0.f; a1o[i] = 0.f; }
#pragma unroll
        for (int ks = 0; ks < 8; ks += 2) {
            bf16x8 kf0e = *(const bf16x8*)(sk + (kb0 ^ (ks * 32)));
            bf16x8 kf1e = *(const bf16x8*)(sk + ((kb0 ^ (ks * 32)) + 8192));
            bf16x8 kf0o = *(const bf16x8*)(sk + (kb0 ^ ((ks + 1) * 32)));
            bf16x8 kf1o = *(const bf16x8*)(sk + ((kb0 ^ ((ks + 1) * 32)) + 8192));
            a0e = __builtin_amdgcn_mfma_f32_32x32x16_bf16(kf0e, qf[ks], a0e, 0, 0, 0);
            a1e = __builtin_amdgcn_mfma_f32_32x32x16_bf16(kf1e, qf[ks], a1e, 0, 0, 0);
            a0o = __builtin_amdgcn_mfma_f32_32x32x16_bf16(kf0o, qf[ks + 1], a0o, 0, 0, 0);
            a1o = __builtin_amdgcn_mfma_f32_32x32x16_bf16(kf1o, qf[ks + 1], a1o, 0, 0, 0);
        }
#pragma unroll
        for (int i = 0; i < 16; i++) { sa0[i] = a0e[i] + a0o[i]; sa1[i] = a1e[i] + a1o[i]; }
    };

    u32 W0[8], W1[8];  // P words of the previous tile (post-swap)
    auto do_softmax = [&]() {
        f32x16 p0, p1;
#pragma unroll
        for (int i = 0; i < 16; i++) { p0[i] = exp2f(sa0[i]); p1[i] = exp2f(sa1[i]); }
        float s0 = ((p0[0] + p0[1]) + (p0[2] + p0[3])) + ((p0[4] + p0[5]) + (p0[6] + p0[7]));
        float s1 = ((p0[8] + p0[9]) + (p0[10] + p0[11])) + ((p0[12] + p0[13]) + (p0[14] + p0[15]));
        float s2 = ((p1[0] + p1[1]) + (p1[2] + p1[3])) + ((p1[4] + p1[5]) + (p1[6] + p1[7]));
        float s3 = ((p1[8] + p1[9]) + (p1[10] + p1[11])) + ((p1[12] + p1[13]) + (p1[14] + p1[15]));
        lrun += (s0 + s1) + (s2 + s3);
#pragma unroll
        for (int j = 0; j < 8; j++) {
            W0[j] = cvt_pk_bf16(p0[2 * j], p0[2 * j + 1]);
            W1[j] = cvt_pk_bf16(p1[2 * j], p1[2 * j + 1]);
        }
        pl32_swap(W0[0], W0[2]); pl32_swap(W0[1], W0[3]);
        pl32_swap(W0[4], W0[6]); pl32_swap(W0[5], W0[7]);
        pl32_swap(W1[0], W1[2]); pl32_swap(W1[1], W1[3]);
        pl32_swap(W1[4], W1[6]); pl32_swap(W1[5], W1[7]);
    };

    auto do_pv = [&](const char* sv) {
#pragma unroll
        for (int s = 0; s < 4; s++) {
            u32x4 fw;
            if (s == 0)      fw = (u32x4){W0[0], W0[1], W0[2], W0[3]};
            else if (s == 1) fw = (u32x4){W0[4], W0[5], W0[6], W0[7]};
            else if (s == 2) fw = (u32x4){W1[0], W1[1], W1[2], W1[3]};
            else             fw = (u32x4){W1[4], W1[5], W1[6], W1[7]};
            bf16x8 pa = __builtin_bit_cast(bf16x8, fw);
            const int coff = (s >> 1) * 64 + (s & 1) * 32;
#pragma unroll
            for (int db = 0; db < 4; db++) {
                bf16x8 vf = *(const bf16x8*)(sv + (vbs[db] ^ coff));
                oacc[db] = __builtin_amdgcn_mfma_f32_32x32x16_bf16(pa, vf, oacc[db], 0, 0, 0);
            }
        }
    };

    // ---- prologue: tile 0
    issue_loads();
    write_lds(0, 0);
    __syncthreads();
    if (nt > 1) issue_loads();
    __builtin_amdgcn_s_setprio(1);
    do_qkt(s_k[0]);
    __builtin_amdgcn_s_setprio(0);
    if (!phase) do_softmax();          // phase-1 waves defer softmax(0) past the next barrier

    // ---- main loop
    int vb_w = 1, vb_r = 0;
    for (int it = 1; it < nt; it++) {
        write_lds(it & 1, vb_w);
        __syncthreads();
        if (it + 1 < nt) issue_loads();
        if (phase) do_softmax();       // softmax(it-1): VALU while phase-0 waves run MFMA
        __builtin_amdgcn_s_setprio(1);
        do_qkt(s_k[it & 1]);
        do_pv(s_vt[vb_r]);
        __builtin_amdgcn_s_setprio(0);
        if (!phase) do_softmax();      // softmax(it)
        vb_r = vb_w;
        vb_w = vb_w + 1 == 3 ? 0 : vb_w + 1;
    }
    // ---- epilogue PV of last tile
    if (phase) do_softmax();           // softmax(nt-1) for deferred waves
    __builtin_amdgcn_s_setprio(1);
    do_pv(s_vt[vb_r]);
    __builtin_amdgcn_s_setprio(0);

    // ---- write unnormalized O (bf16) + l
    size_t obase = (((size_t)split * BB + b) * NN + q0 + w * 32);
    float ls = lrun + __shfl_xor(lrun, 32);
    if (lane < 32) {
        Lw[obase + lq] = ls;
    }
#pragma unroll
    for (int r = 0; r < 16; r++) {
        int qrow = (r & 3) + 8 * (r >> 2) + 4 * hi;
        bf16* op = Opart + (obase + qrow) * CK + lq;
#pragma unroll
        for (int db = 0; db < 4; db++) op[db * 32] = (bf16)oacc[db][r];
    }
}

// ---------------- Kernel 2b: combine KV-split partials (m==0: plain sums, bf16 Opart) ----------------
__global__ __launch_bounds__(256) void k_combine(
    const bf16* __restrict__ Opart, const float* __restrict__ Lw,
    bf16* __restrict__ ao, int nsplit)
{
    const int t = threadIdx.x;
    const int b = blockIdx.y;
    const int r0 = blockIdx.x * 64;
    const int d4 = (t & 31) * 4;
#pragma unroll
    for (int p = 0; p < 8; p++) {
        int row = r0 + (t >> 5) + p * 8;
        size_t rbase = (size_t)b * NN + row;
        float L = 0.f;
        float4 acc = {0.f, 0.f, 0.f, 0.f};
        for (int s = 0; s < nsplit; s++) {
            size_t sb = ((size_t)s * BB) * NN + rbase;
            L += Lw[sb];
            bf16x4 v = *(const bf16x4*)(Opart + sb * CK + d4);
            acc.x += (float)v[0]; acc.y += (float)v[1];
            acc.z += (float)v[2]; acc.w += (float)v[3];
        }
        float inv = 1.f / L;
        bf16x4 o4 = { (bf16)(acc.x * inv), (bf16)(acc.y * inv),
                      (bf16)(acc.z * inv), (bf16)(acc.w * inv) };
        *(bf16x4*)(ao + rbase * CK + d4) = o4;
    }
}

// ---------------- Kernel 3: folded output projection + bias + residual ----------------
__global__ __launch_bounds__(256) void k_out(
    const float* __restrict__ x, const float* __restrict__ Wo, const float* __restrict__ bo,
    const bf16* __restrict__ ao, float* __restrict__ y)
{
    const int t = threadIdx.x;
    const int lane = t & 63, w = t >> 6;
    const int lr = lane & 15, lg = lane >> 4;
    const int n0 = blockIdx.x * 128;
    const int o0 = blockIdx.y * 64;
    const int b = blockIdx.z;

    __shared__ __align__(16) char s_w[64 * 256];
    __shared__ __align__(16) char s_a[128 * 256];

    {
        int c4 = (t & 31) * 4, rbase = t >> 5;
#pragma unroll
        for (int p = 0; p < 8; p++) {
            int row = rbase + p * 8;
            const float* wp = Wo + (size_t)(o0 + row) * C + c4;
            float4 a0 = *(const float4*)(wp);
            float4 a1 = *(const float4*)(wp + 128);
            float4 a2 = *(const float4*)(wp + 256);
            float4 a3 = *(const float4*)(wp + 384);
            bf16x4 r4 = { (bf16)(a0.x + a1.x + a2.x + a3.x), (bf16)(a0.y + a1.y + a2.y + a3.y),
                          (bf16)(a0.z + a1.z + a2.z + a3.z), (bf16)(a0.w + a1.w + a2.w + a3.w) };
            int off = (row * 256 + c4 * 2) ^ ((row & 7) << 4);
            *(bf16x4*)(s_w + off) = r4;
        }
    }
    {
        int chunk = t & 15, rbase = t >> 4;
#pragma unroll
        for (int p = 0; p < 8; p++) {
            int row = rbase + p * 16;
            bf16x8 v = *(const bf16x8*)(ao + ((size_t)b * NN + n0 + row) * CK + chunk * 8);
            int off = (row * 256 + chunk * 16) ^ ((row & 7) << 4);
            *(bf16x8*)(s_a + off) = v;
        }
    }
    __syncthreads();

    f32x4 acc[8];
#pragma unroll
    for (int j = 0; j < 8; j++) acc[j] = (f32x4){0.f, 0.f, 0.f, 0.f};
#pragma unroll
    for (int ks = 0; ks < 4; ks++) {
        int row = w * 16 + lr;
        int aoff = (row * 256 + (ks * 32 + lg * 8) * 2) ^ ((row & 7) << 4);
        bf16x8 wf = *(const bf16x8*)(s_w + aoff);
#pragma unroll
        for (int j = 0; j < 8; j++) {
            int nrow = j * 16 + lr;
            int boff = (nrow * 256 + (ks * 32 + lg * 8) * 2) ^ ((nrow & 7) << 4);
            bf16x8 af = *(const bf16x8*)(s_a + boff);
            acc[j] = __builtin_amdgcn_mfma_f32_16x16x32_bf16(wf, af, acc[j], 0, 0, 0);
        }
    }
#pragma unroll
    for (int j = 0; j < 8; j++) {
        int n = n0 + j * 16 + lr;
#pragma unroll
        for (int r = 0; r < 4; r++) {
            int o = o0 + w * 16 + lg * 4 + r;
            size_t idx = ((size_t)b * C + o) * NN + n;
            y[idx] = acc[j][r] + bo[o] + x[idx];
        }
    }
}

extern "C" void kernel_launch(void* const* d_in, const int* in_sizes, int n_in,
                              void* d_out, int out_size, void* d_ws, size_t ws_size,
                              hipStream_t stream)
{
    const float* x  = (const float*)d_in[0];
    const float* Wq = (const float*)d_in[1];
    const float* bq = (const float*)d_in[2];
    const float* Wk = (const float*)d_in[3];
    const float* bk = (const float*)d_in[4];
    const float* Wv = (const float*)d_in[5];
    const float* bv = (const float*)d_in[6];
    const float* Wo = (const float*)d_in[7];
    const float* bo = (const float*)d_in[8];
    float* y = (float*)d_out;

    const size_t qkv_elems = (size_t)3 * BB * NN * CK;   // bf16
    const size_t ao_elems  = (size_t)BB * NN * CK;       // bf16

    bf16* qkv = (bf16*)d_ws;
    bf16* ao  = qkv + qkv_elems;
    bf16* Opart = ao + ao_elems;

    int nsplit = 4;
    {
        size_t fixed = (qkv_elems + ao_elems) * sizeof(bf16);
        size_t per_split = (size_t)BB * NN * CK * sizeof(bf16) + (size_t)BB * NN * sizeof(float);
        while (nsplit > 1 && fixed + (size_t)nsplit * per_split > ws_size) nsplit >>= 1;
    }
    float* Lw = (float*)(Opart + (size_t)nsplit * BB * NN * CK);

    k_qkv<<<dim3(384, 1, 1), 256, 0, stream>>>(x, Wq, bq, Wk, bk, Wv, bv, qkv);
    k_attn<<<dim3(32 * BB * nsplit, 1, 1), 512, 0, stream>>>(qkv, Opart, Lw, nsplit);
    k_combine<<<dim3(NN / 64, BB), 256, 0, stream>>>(Opart, Lw, ao, nsplit);
    k_out<<<dim3(NN / 128, C / 64, BB), 256, 0, stream>>>(x, Wo, bo, ao, y);
}

// Round 15
// 134.608 us; speedup vs baseline: 1.0724x; 1.0724x over previous
//
#include <hip/hip_runtime.h>
#include <hip/hip_bf16.h>

typedef __bf16 bf16;
typedef __bf16 bf16x8 __attribute__((ext_vector_type(8)));
typedef __bf16 bf16x4 __attribute__((ext_vector_type(4)));
typedef float  f32x4  __attribute__((ext_vector_type(4)));
typedef float  f32x16 __attribute__((ext_vector_type(16)));
typedef unsigned int u32;
typedef u32 u32x4 __attribute__((ext_vector_type(4)));

constexpr int BB = 2, C = 512, NN = 8192, CK = 128;

__device__ __forceinline__ u32 cvt_pk_bf16(float lo, float hi) {
    u32 r;
    asm("v_cvt_pk_bf16_f32 %0, %1, %2" : "=v"(r) : "v"(lo), "v"(hi));
    return r;
}
__device__ __forceinline__ void pl32_swap(u32& a, u32& b) {
    asm("v_permlane32_swap_b32 %0, %1" : "+v"(a), "+v"(b));
}

// ---------------- Kernel 1: QKV projection, XCD-swizzled (x re-reads hit L2) ----------------
__global__ __launch_bounds__(256) void k_qkv(
    const float* __restrict__ x,
    const float* __restrict__ Wq, const float* __restrict__ bq,
    const float* __restrict__ Wk, const float* __restrict__ bk,
    const float* __restrict__ Wv, const float* __restrict__ bv,
    bf16* __restrict__ qkv_ws)
{
    const int t = threadIdx.x;
    const int lane = t & 63, w = t >> 6;
    const int lr = lane & 15, lg = lane >> 4;

    const int lin = blockIdx.x;
    const int rid = (lin & 7) * 48 + (lin >> 3);   // bijective over 384
    const int n0 = (rid / 6) * 128;
    const int sub = rid % 6;
    const int which = sub >> 1;
    const int b = sub & 1;

    const float* W    = which == 0 ? Wq : (which == 1 ? Wk : Wv);
    const float* bias = which == 0 ? bq : (which == 1 ? bk : bv);
    bf16* out = qkv_ws + (size_t)which * BB * NN * CK;

    __shared__ __align__(16) char s_xT[128 * 144];
    __shared__ __align__(16) char s_w [128 * 144];

    f32x4 acc[2][8];
#pragma unroll
    for (int m = 0; m < 2; m++)
#pragma unroll
        for (int j = 0; j < 8; j++) acc[m][j] = (f32x4){0.f, 0.f, 0.f, 0.f};

    const float* xb = x + (size_t)b * C * NN;

    const int tok4 = (t & 31) * 4;
    const int c8   = (t >> 5) * 8;
    const int ob   = t >> 2;
    const int c16  = (t & 3) * 16;

    for (int kt = 0; kt < C; kt += 64) {
        __syncthreads();
        {
            float4 v[8];
#pragma unroll
            for (int i = 0; i < 8; i++)
                v[i] = *(const float4*)(xb + (size_t)(kt + c8 + i) * NN + n0 + tok4);
#pragma unroll
            for (int j = 0; j < 4; j++) {
                int tok = tok4 + j;
                bf16x8 pk = { (bf16)v[0].x, (bf16)v[1].x, (bf16)v[2].x, (bf16)v[3].x,
                              (bf16)v[4].x, (bf16)v[5].x, (bf16)v[6].x, (bf16)v[7].x };
                if (j == 1) pk = (bf16x8){ (bf16)v[0].y, (bf16)v[1].y, (bf16)v[2].y, (bf16)v[3].y,
                                           (bf16)v[4].y, (bf16)v[5].y, (bf16)v[6].y, (bf16)v[7].y };
                if (j == 2) pk = (bf16x8){ (bf16)v[0].z, (bf16)v[1].z, (bf16)v[2].z, (bf16)v[3].z,
                                           (bf16)v[4].z, (bf16)v[5].z, (bf16)v[6].z, (bf16)v[7].z };
                if (j == 3) pk = (bf16x8){ (bf16)v[0].w, (bf16)v[1].w, (bf16)v[2].w, (bf16)v[3].w,
                                           (bf16)v[4].w, (bf16)v[5].w, (bf16)v[6].w, (bf16)v[7].w };
                int off = tok * 144 + ((c8 * 2) ^ ((((tok >> 2) & 7)) << 4));
                *(bf16x8*)(s_xT + off) = pk;
            }
        }
#pragma unroll
        for (int p = 0; p < 2; p++) {
            int o = ob + p * 64;
            const float* wp = W + (size_t)o * C + kt + c16;
            float4 a0 = *(const float4*)(wp);
            float4 a1 = *(const float4*)(wp + 4);
            float4 a2 = *(const float4*)(wp + 8);
            float4 a3 = *(const float4*)(wp + 12);
            bf16x8 p0 = { (bf16)a0.x, (bf16)a0.y, (bf16)a0.z, (bf16)a0.w,
                          (bf16)a1.x, (bf16)a1.y, (bf16)a1.z, (bf16)a1.w };
            bf16x8 p1 = { (bf16)a2.x, (bf16)a2.y, (bf16)a2.z, (bf16)a2.w,
                          (bf16)a3.x, (bf16)a3.y, (bf16)a3.z, (bf16)a3.w };
            int perm = ((o >> 2) & 7) << 4;
            *(bf16x8*)(s_w + o * 144 + ((c16 * 2) ^ perm)) = p0;
            *(bf16x8*)(s_w + o * 144 + ((c16 * 2 + 16) ^ perm)) = p1;
        }
        __syncthreads();
#pragma unroll
        for (int ks = 0; ks < 2; ks++) {
            bf16x8 af[2];
#pragma unroll
            for (int m = 0; m < 2; m++) {
                int row = w * 32 + m * 16 + lr;
                af[m] = *(const bf16x8*)(s_xT + row * 144 + ((ks * 64 + lg * 16) ^ ((((row >> 2) & 7)) << 4)));
            }
#pragma unroll
            for (int j = 0; j < 8; j++) {
                int row = j * 16 + lr;
                bf16x8 bfr = *(const bf16x8*)(s_w + row * 144 + ((ks * 64 + lg * 16) ^ ((((row >> 2) & 7)) << 4)));
                acc[0][j] = __builtin_amdgcn_mfma_f32_16x16x32_bf16(af[0], bfr, acc[0][j], 0, 0, 0);
                acc[1][j] = __builtin_amdgcn_mfma_f32_16x16x32_bf16(af[1], bfr, acc[1][j], 0, 0, 0);
            }
        }
    }
#pragma unroll
    for (int m = 0; m < 2; m++)
#pragma unroll
        for (int j = 0; j < 8; j++) {
            int o = j * 16 + lr;
            float bia = bias[o];
#pragma unroll
            for (int r = 0; r < 4; r++) {
                int tok = n0 + w * 32 + m * 16 + lg * 4 + r;
                out[((size_t)b * NN + tok) * CK + o] = (bf16)(acc[m][j][r] + bia);
            }
        }
}

// ---------------- Kernel 2: flash attention, m==0, pipelined PV, anti-phase skew, bf16 Opart ----------------
__global__ __launch_bounds__(512, 2) void k_attn(
    const bf16* __restrict__ qkv_ws,
    bf16* __restrict__ Opart, float* __restrict__ Lw,
    int nsplit)
{
    const int t = threadIdx.x;
    const int lane = t & 63, w = t >> 6;      // 8 waves
    const int lq = lane & 31, hi = lane >> 5;
    const int phase = (w >> 2) & 1;           // one of each phase per SIMD

    const int total = 32 * BB * nsplit;
    const int chunkv = total >> 3;
    const int lin = blockIdx.x;
    const int rid = (lin & 7) * chunkv + (lin >> 3);
    const int qt = rid & 31;                  // 32 q-tiles of 256
    const int bs = rid >> 5;
    const int b = bs & 1, split = bs >> 1;

    const int q0 = qt * 256;
    const int kbeg = split * (NN / nsplit);
    const int nt = (NN / nsplit) / 64;

    const bf16* kg = qkv_ws + (size_t)BB * NN * CK;
    const bf16* vg = qkv_ws + (size_t)2 * BB * NN * CK;

    __shared__ __align__(16) char s_k[2][64 * 256];    // [key][dim], swz ((key&7)<<4)
    __shared__ __align__(16) char s_vt[3][128 * 128];  // [dim][key], swz (((d^(d>>3))&7)<<4)

    // per-lane LDS read bases (hi folded in)
    const int kb0 = lq * 256 + ((((lq & 7) ^ hi)) << 4);
    int vbs[4];
#pragma unroll
    for (int db = 0; db < 4; db++) {
        int d = db * 32 + lq;
        vbs[db] = d * 128 + (((((d ^ (d >> 3)) & 7) ^ hi)) << 4);
    }
    // staging (role-split: waves 0-3 K, 4-7 V^T)
    const int t2 = t & 255;
    const int sc = t2 & 15, sr = t2 >> 4;
    const int kw_base = (sr * 256 + sc * 16) ^ ((sr & 7) << 4);
    const int vw_base = (sc * 1024 + sr * 8) ^ ((sc & 7) << 4);

    // Q fragments pre-scaled by scale*log2e
    bf16x8 qf[8];
    {
        const float qs = 0.08838834764831845f * 1.4426950408889634f;
        const bf16* qp = qkv_ws + ((size_t)b * NN + q0 + w * 32 + lq) * CK + hi * 8;
#pragma unroll
        for (int ks = 0; ks < 8; ks++) {
            bf16x8 v = *(const bf16x8*)(qp + ks * 16);
#pragma unroll
            for (int i = 0; i < 8; i++) qf[ks][i] = (bf16)((float)v[i] * qs);
        }
    }

    f32x16 oacc[4];
#pragma unroll
    for (int db = 0; db < 4; db++)
#pragma unroll
        for (int i = 0; i < 16; i++) oacc[db][i] = 0.f;
    float lrun = 0.f;

    const bf16* kp = kg + ((size_t)b * NN + kbeg + sr) * CK + sc * 8;
    const bf16* vp = vg + ((size_t)b * NN + kbeg + sr * 4) * CK + sc * 8;
    bf16x8 stg[4];

    auto issue_loads = [&]() {
        if (w < 4) {
#pragma unroll
            for (int p = 0; p < 4; p++) stg[p] = *(const bf16x8*)(kp + (size_t)(16 * p) * CK);
        } else {
#pragma unroll
            for (int p = 0; p < 4; p++) stg[p] = *(const bf16x8*)(vp + (size_t)p * CK);
        }
        kp += (size_t)64 * CK;
        vp += (size_t)64 * CK;
    };

    auto write_lds = [&](int kbuf, int vbuf) {
        if (w < 4) {
            char* skw = s_k[kbuf] + kw_base;
#pragma unroll
            for (int p = 0; p < 4; p++)
                *(bf16x8*)(skw + p * 4096) = stg[p];
        } else {
            char* svw = s_vt[vbuf];
#pragma unroll
            for (int i = 0; i < 8; i++) {
                bf16x4 pk = { stg[0][i], stg[1][i], stg[2][i], stg[3][i] };
                *(bf16x4*)(svw + (vw_base ^ (i * 144))) = pk;   // i*128 | i*16
            }
        }
    };

    f32x16 sa0, sa1;
    auto do_qkt = [&](const char* sk) {
#pragma unroll
        for (int i = 0; i < 16; i++) { sa0[i] = 0.f; sa1[i] = 0.f; }
#pragma unroll
        for (int ks = 0; ks < 8; ks++) {
            bf16x8 kf0 = *(const bf16x8*)(sk + (kb0 ^ (ks * 32)));
            bf16x8 kf1 = *(const bf16x8*)(sk + ((kb0 ^ (ks * 32)) + 8192));
            sa0 = __builtin_amdgcn_mfma_f32_32x32x16_bf16(kf0, qf[ks], sa0, 0, 0, 0);
            sa1 = __builtin_amdgcn_mfma_f32_32x32x16_bf16(kf1, qf[ks], sa1, 0, 0, 0);
        }
    };

    u32 W0[8], W1[8];  // P words of the previous tile (post-swap)
    auto do_softmax = [&]() {
        f32x16 p0, p1;
#pragma unroll
        for (int i = 0; i < 16; i++) { p0[i] = exp2f(sa0[i]); p1[i] = exp2f(sa1[i]); }
        float s0 = ((p0[0] + p0[1]) + (p0[2] + p0[3])) + ((p0[4] + p0[5]) + (p0[6] + p0[7]));
        float s1 = ((p0[8] + p0[9]) + (p0[10] + p0[11])) + ((p0[12] + p0[13]) + (p0[14] + p0[15]));
        float s2 = ((p1[0] + p1[1]) + (p1[2] + p1[3])) + ((p1[4] + p1[5]) + (p1[6] + p1[7]));
        float s3 = ((p1[8] + p1[9]) + (p1[10] + p1[11])) + ((p1[12] + p1[13]) + (p1[14] + p1[15]));
        lrun += (s0 + s1) + (s2 + s3);
#pragma unroll
        for (int j = 0; j < 8; j++) {
            W0[j] = cvt_pk_bf16(p0[2 * j], p0[2 * j + 1]);
            W1[j] = cvt_pk_bf16(p1[2 * j], p1[2 * j + 1]);
        }
        pl32_swap(W0[0], W0[2]); pl32_swap(W0[1], W0[3]);
        pl32_swap(W0[4], W0[6]); pl32_swap(W0[5], W0[7]);
        pl32_swap(W1[0], W1[2]); pl32_swap(W1[1], W1[3]);
        pl32_swap(W1[4], W1[6]); pl32_swap(W1[5], W1[7]);
    };

    auto do_pv = [&](const char* sv) {
#pragma unroll
        for (int s = 0; s < 4; s++) {
            u32x4 fw;
            if (s == 0)      fw = (u32x4){W0[0], W0[1], W0[2], W0[3]};
            else if (s == 1) fw = (u32x4){W0[4], W0[5], W0[6], W0[7]};
            else if (s == 2) fw = (u32x4){W1[0], W1[1], W1[2], W1[3]};
            else             fw = (u32x4){W1[4], W1[5], W1[6], W1[7]};
            bf16x8 pa = __builtin_bit_cast(bf16x8, fw);
            const int coff = (s >> 1) * 64 + (s & 1) * 32;
#pragma unroll
            for (int db = 0; db < 4; db++) {
                bf16x8 vf = *(const bf16x8*)(sv + (vbs[db] ^ coff));
                oacc[db] = __builtin_amdgcn_mfma_f32_32x32x16_bf16(pa, vf, oacc[db], 0, 0, 0);
            }
        }
    };

    // ---- prologue: tile 0
    issue_loads();
    write_lds(0, 0);
    __syncthreads();
    if (nt > 1) issue_loads();
    __builtin_amdgcn_s_setprio(1);
    do_qkt(s_k[0]);
    __builtin_amdgcn_s_setprio(0);
    if (!phase) do_softmax();          // phase-1 waves defer softmax(0) past the next barrier

    // ---- main loop
    int vb_w = 1, vb_r = 0;
    for (int it = 1; it < nt; it++) {
        write_lds(it & 1, vb_w);
        __syncthreads();
        if (it + 1 < nt) issue_loads();
        if (phase) do_softmax();       // softmax(it-1): VALU while phase-0 waves run MFMA
        __builtin_amdgcn_s_setprio(1);
        do_qkt(s_k[it & 1]);
        do_pv(s_vt[vb_r]);
        __builtin_amdgcn_s_setprio(0);
        if (!phase) do_softmax();      // softmax(it)
        vb_r = vb_w;
        vb_w = vb_w + 1 == 3 ? 0 : vb_w + 1;
    }
    // ---- epilogue PV of last tile
    if (phase) do_softmax();           // softmax(nt-1) for deferred waves
    __builtin_amdgcn_s_setprio(1);
    do_pv(s_vt[vb_r]);
    __builtin_amdgcn_s_setprio(0);

    // ---- write unnormalized O (bf16) + l
    size_t obase = (((size_t)split * BB + b) * NN + q0 + w * 32);
    float ls = lrun + __shfl_xor(lrun, 32);
    if (lane < 32) {
        Lw[obase + lq] = ls;
    }
#pragma unroll
    for (int r = 0; r < 16; r++) {
        int qrow = (r & 3) + 8 * (r >> 2) + 4 * hi;
        bf16* op = Opart + (obase + qrow) * CK + lq;
#pragma unroll
        for (int db = 0; db < 4; db++) op[db * 32] = (bf16)oacc[db][r];
    }
}

// ---------------- Kernel 3: fused combine + output projection + bias + residual ----------------
// Stages sum_s(Opart)/L directly, then Woe GEMM. No separate combine kernel.
__global__ __launch_bounds__(256) void k_out(
    const float* __restrict__ x, const float* __restrict__ Wo, const float* __restrict__ bo,
    const bf16* __restrict__ Opart, const float* __restrict__ Lw,
    float* __restrict__ y, int nsplit)
{
    const int t = threadIdx.x;
    const int lane = t & 63, w = t >> 6;
    const int lr = lane & 15, lg = lane >> 4;
    const int n0 = blockIdx.x * 128;
    const int o0 = blockIdx.y * 64;
    const int b = blockIdx.z;

    __shared__ __align__(16) char s_w[64 * 256];
    __shared__ __align__(16) char s_a[128 * 256];
    __shared__ float s_linv[128];

    // phase A: per-row 1/L
    if (t < 128) {
        int row = n0 + t;
        float L = 0.f;
        for (int s = 0; s < nsplit; s++)
            L += Lw[((size_t)s * BB + b) * NN + row];
        s_linv[t] = 1.f / L;
    }
    // stage folded Wo (independent of s_linv)
    {
        int c4 = (t & 31) * 4, rbase = t >> 5;
#pragma unroll
        for (int p = 0; p < 8; p++) {
            int row = rbase + p * 8;
            const float* wp = Wo + (size_t)(o0 + row) * C + c4;
            float4 a0 = *(const float4*)(wp);
            float4 a1 = *(const float4*)(wp + 128);
            float4 a2 = *(const float4*)(wp + 256);
            float4 a3 = *(const float4*)(wp + 384);
            bf16x4 r4 = { (bf16)(a0.x + a1.x + a2.x + a3.x), (bf16)(a0.y + a1.y + a2.y + a3.y),
                          (bf16)(a0.z + a1.z + a2.z + a3.z), (bf16)(a0.w + a1.w + a2.w + a3.w) };
            int off = (row * 256 + c4 * 2) ^ ((row & 7) << 4);
            *(bf16x4*)(s_w + off) = r4;
        }
    }
    __syncthreads();   // s_linv ready
    // stage ao = (sum_s Opart)/L, bf16 into LDS
    {
        int chunk = t & 15, rbase = t >> 4;
#pragma unroll
        for (int p = 0; p < 8; p++) {
            int row = rbase + p * 16;
            float accv[8];
#pragma unroll
            for (int i = 0; i < 8; i++) accv[i] = 0.f;
            for (int s = 0; s < nsplit; s++) {
                const bf16* op = Opart + (((size_t)s * BB + b) * NN + n0 + row) * CK + chunk * 8;
                bf16x8 v = *(const bf16x8*)op;
#pragma unroll
                for (int i = 0; i < 8; i++) accv[i] += (float)v[i];
            }
            float inv = s_linv[row];
            bf16x8 outv;
#pragma unroll
            for (int i = 0; i < 8; i++) outv[i] = (bf16)(accv[i] * inv);
            int off = (row * 256 + chunk * 16) ^ ((row & 7) << 4);
            *(bf16x8*)(s_a + off) = outv;
        }
    }
    __syncthreads();

    f32x4 acc[8];
#pragma unroll
    for (int j = 0; j < 8; j++) acc[j] = (f32x4){0.f, 0.f, 0.f, 0.f};
#pragma unroll
    for (int ks = 0; ks < 4; ks++) {
        int row = w * 16 + lr;
        int aoff = (row * 256 + (ks * 32 + lg * 8) * 2) ^ ((row & 7) << 4);
        bf16x8 wf = *(const bf16x8*)(s_w + aoff);
#pragma unroll
        for (int j = 0; j < 8; j++) {
            int nrow = j * 16 + lr;
            int boff = (nrow * 256 + (ks * 32 + lg * 8) * 2) ^ ((nrow & 7) << 4);
            bf16x8 af = *(const bf16x8*)(s_a + boff);
            acc[j] = __builtin_amdgcn_mfma_f32_16x16x32_bf16(wf, af, acc[j], 0, 0, 0);
        }
    }
#pragma unroll
    for (int j = 0; j < 8; j++) {
        int n = n0 + j * 16 + lr;
#pragma unroll
        for (int r = 0; r < 4; r++) {
            int o = o0 + w * 16 + lg * 4 + r;
            size_t idx = ((size_t)b * C + o) * NN + n;
            y[idx] = acc[j][r] + bo[o] + x[idx];
        }
    }
}

extern "C" void kernel_launch(void* const* d_in, const int* in_sizes, int n_in,
                              void* d_out, int out_size, void* d_ws, size_t ws_size,
                              hipStream_t stream)
{
    const float* x  = (const float*)d_in[0];
    const float* Wq = (const float*)d_in[1];
    const float* bq = (const float*)d_in[2];
    const float* Wk = (const float*)d_in[3];
    const float* bk = (const float*)d_in[4];
    const float* Wv = (const float*)d_in[5];
    const float* bv = (const float*)d_in[6];
    const float* Wo = (const float*)d_in[7];
    const float* bo = (const float*)d_in[8];
    float* y = (float*)d_out;

    const size_t qkv_elems = (size_t)3 * BB * NN * CK;   // bf16

    bf16* qkv = (bf16*)d_ws;
    bf16* Opart = qkv + qkv_elems;

    int nsplit = 4;
    {
        size_t fixed = qkv_elems * sizeof(bf16);
        size_t per_split = (size_t)BB * NN * CK * sizeof(bf16) + (size_t)BB * NN * sizeof(float);
        while (nsplit > 1 && fixed + (size_t)nsplit * per_split > ws_size) nsplit >>= 1;
    }
    float* Lw = (float*)(Opart + (size_t)nsplit * BB * NN * CK);

    k_qkv<<<dim3(384, 1, 1), 256, 0, stream>>>(x, Wq, bq, Wk, bk, Wv, bv, qkv);
    k_attn<<<dim3(32 * BB * nsplit, 1, 1), 512, 0, stream>>>(qkv, Opart, Lw, nsplit);
    k_out<<<dim3(NN / 128, C / 64, BB), 256, 0, stream>>>(x, Wo, bo, Opart, Lw, y, nsplit);
}